// Round 6
// baseline (119.852 us; speedup 1.0000x reference)
//
#include <hip/hip_runtime.h>

// Vanilla RNN B=4096 S=512 I=1 H=16 O=1 — serial-chain latency optimization.
// Lane = (batch, h-row); 16 lanes/batch; 1024 waves = 1 wave/SIMD (hard cap).
// Wall time = 512 * per-step critical-path latency.
//
// R5: TRANS-FREE tanh. Evidence (R2/R3/R4b all ~230-270 cyc/step with the
// same exp2->add->rcp tail but different fronts): v_exp/v_rcp dependent
// latency on a solo wave is ~60-90 cyc each. Replace with:
//   tanh(z) = z*P(z^2)/Q(z^2)   (Eigen float coefficients, clamp +-7.905)
//   1/Q via bit-trick seed 0x7EF311C3 + 2 Newton steps (all 5-cyc VALU).
// P(u) runs in parallel with Q->rcp->Newton; serial tail depth ~7 hops.
// Front: pack (quad_perm swap + pkrtz), 7 off-path packed rotations,
// 8 fdot2 (f32 acc) in 4 chains + tree. Weights self-calibrated against
// the HW's actual DPP permutations (verified R1..R4b). f16 only for the
// dot inputs (R3/R4b measured ~1-2e-3 final absmax; threshold 5.6e-3).

typedef __fp16 half2_ __attribute__((ext_vector_type(2)));
typedef float float4_ __attribute__((ext_vector_type(4)));

#define ROTI(v, N)  __builtin_amdgcn_mov_dpp((v), 0x120 + (N), 0xF, 0xF, 0)
#define ROTF(v, N)  __int_as_float(__builtin_amdgcn_mov_dpp(__float_as_int(v), 0x120 + (N), 0xF, 0xF, 0))
#define ROTP(v, N)  __builtin_bit_cast(half2_, __builtin_amdgcn_mov_dpp(__builtin_bit_cast(int, (v)), 0x120 + (N), 0xF, 0xF, 0))
// quad_perm [1,0,3,2]: lane i gets lane i^1  (ctrl = 1 | 0<<2 | 3<<4 | 2<<6)
#define SWP1F(v)    __int_as_float(__builtin_amdgcn_mov_dpp(__float_as_int(v), 0x0B1, 0xF, 0xF, 0))
#define SWP1I(v)    __builtin_amdgcn_mov_dpp((v), 0x0B1, 0xF, 0xF, 0)

// Eigen generic_fast_tanh_float coefficients (float-accurate rational).
#define A1  4.89352455891786e-03f
#define A3  6.37261928875436e-04f
#define A5  1.48572235717979e-05f
#define A7  5.12229709037114e-08f
#define A9  -8.60467152213735e-11f
#define A11 2.00018790482477e-13f
#define A13 -2.76076847742355e-16f
#define B0  4.89352518554385e-03f
#define B2  2.26843463243900e-03f
#define B4  1.18534705686654e-04f
#define B6  1.19825839466702e-06f
#define TCLAMP 7.90531110763549805f

__global__ __launch_bounds__(64) void rnn_kernel(
    const float* __restrict__ x,
    const float* __restrict__ W_ih,
    const float* __restrict__ W_hh,
    const float* __restrict__ b_ih,
    const float* __restrict__ b_hh,
    const float* __restrict__ W_fc,
    const float* __restrict__ b_fc,
    float* __restrict__ out)
{
    const int li = (int)(threadIdx.x & 15u);
    const int b  = (int)((blockIdx.x * 64u + threadIdx.x) >> 4);

    const float* __restrict__ row = W_hh + li * 16;

    // Self-calibrated packed weights. Arriving pair at lane i from ROTP(pk,2k)
    // is (h_s, h_{s^1}) with s = rho_{2k}(i); weights must match that order.
    half2_ w2[8];
    {
        int s0 = li;
        w2[0][0] = (__fp16)row[s0];
        w2[0][1] = (__fp16)row[s0 ^ 1];
#define LW(K, N) { int s_ = ROTI(li, N); \
        w2[K][0] = (__fp16)row[s_]; \
        w2[K][1] = (__fp16)row[s_ ^ 1]; }
        LW(1, 2) LW(2, 4) LW(3, 6) LW(4, 8) LW(5, 10) LW(6, 12) LW(7, 14)
#undef LW
    }

    const float wih  = W_ih[li];
    const float bias = b_ih[li] + b_hh[li];
    const float wfc  = W_fc[li];
    const float bfc  = b_fc[0];

    const float4_* __restrict__ xv = (const float4_*)(x + (size_t)b * 512);

    float h = 0.0f;
    float4_ xc = xv[0];
    float4_ xn = xv[1];

    // One step: pack -> rotations (off-path) -> 8 fdot2 -> tree ->
    // clamp -> rational tanh with bit-trick reciprocal (no trans ops).
#define STEP(XP) do { \
    float sw_ = SWP1F(h); \
    half2_ pk0 = __builtin_amdgcn_cvt_pkrtz(h, sw_); \
    half2_ p2_  = ROTP(pk0, 2); \
    half2_ p4_  = ROTP(pk0, 4); \
    half2_ p6_  = ROTP(pk0, 6); \
    half2_ p8_  = ROTP(pk0, 8); \
    half2_ p10_ = ROTP(pk0, 10); \
    half2_ p12_ = ROTP(pk0, 12); \
    half2_ p14_ = ROTP(pk0, 14); \
    float c0_ = __builtin_amdgcn_fdot2(pk0,  w2[0], (XP), false); \
    c0_ = __builtin_amdgcn_fdot2(p2_,  w2[1], c0_, false); \
    float c1_ = __builtin_amdgcn_fdot2(p4_,  w2[2], 0.0f, false); \
    c1_ = __builtin_amdgcn_fdot2(p6_,  w2[3], c1_, false); \
    float c2_ = __builtin_amdgcn_fdot2(p8_,  w2[4], 0.0f, false); \
    c2_ = __builtin_amdgcn_fdot2(p10_, w2[5], c2_, false); \
    float c3_ = __builtin_amdgcn_fdot2(p12_, w2[6], 0.0f, false); \
    c3_ = __builtin_amdgcn_fdot2(p14_, w2[7], c3_, false); \
    float z_ = (c0_ + c1_) + (c2_ + c3_); \
    z_ = fminf(fmaxf(z_, -TCLAMP), TCLAMP); \
    float u_  = z_ * z_; \
    float u2_ = u_ * u_; \
    /* Q chain (critical): depth 2 from u, then rcp-newton */ \
    float q_ = fmaf(u2_, fmaf(u_, B6, B4), fmaf(u_, B2, B0)); \
    float r_ = __int_as_float(0x7EF311C3 - __float_as_int(q_)); \
    r_ = r_ * fmaf(-q_, r_, 2.0f); \
    r_ = r_ * fmaf(-q_, r_, 2.0f); \
    /* P chain (parallel with Q/rcp) */ \
    float e0_ = fmaf(u_, A3, A1); \
    float e1_ = fmaf(u_, A7, A5); \
    float e2_ = fmaf(u_, A11, A9); \
    float u4_ = u2_ * u2_; \
    float f0_ = fmaf(u2_, e1_, e0_); \
    float f1_ = fmaf(u2_, A13, e2_); \
    float pz_ = fmaf(u4_, f1_, f0_) * z_; \
    h = pz_ * r_; \
} while (0)

#pragma unroll 1
    for (int c = 0; c < 128; ++c) {
        float4_ xf = xv[(c + 2) & 127];  // prefetch (wraps harmlessly)
        // x-projections (x-only) issue inside the chain's stall windows.
        float xp0 = fmaf(xc[0], wih, bias);
        float xp1 = fmaf(xc[1], wih, bias);
        float xp2 = fmaf(xc[2], wih, bias);
        float xp3 = fmaf(xc[3], wih, bias);
        STEP(xp0);
        STEP(xp1);
        STEP(xp2);
        STEP(xp3);
        xc = xn;
        xn = xf;
    }
#undef STEP

    // out[b] = sum_i wfc_i * h_i + bfc  (exact f32 h; rotation reduce).
    float p = h * wfc;
    p += ROTF(p, 8);
    p += ROTF(p, 4);
    p += ROTF(p, 2);
    p += ROTF(p, 1);
    if (li == 0) out[b] = p + bfc;
}

extern "C" void kernel_launch(void* const* d_in, const int* in_sizes, int n_in,
                              void* d_out, int out_size, void* d_ws, size_t ws_size,
                              hipStream_t stream) {
    const float* x    = (const float*)d_in[0];
    const float* W_ih = (const float*)d_in[1];
    const float* W_hh = (const float*)d_in[2];
    const float* b_ih = (const float*)d_in[3];
    const float* b_hh = (const float*)d_in[4];
    const float* W_fc = (const float*)d_in[5];
    const float* b_fc = (const float*)d_in[6];
    float* out = (float*)d_out;

    rnn_kernel<<<1024, 64, 0, stream>>>(x, W_ih, W_hh, b_ih, b_hh, W_fc, b_fc, out);
}

// Round 7
// 102.752 us; speedup vs baseline: 1.1664x; 1.1664x over previous
//
#include <hip/hip_runtime.h>

// Vanilla RNN B=4096 S=512 I=1 H=16 O=1 — serial-chain + load-pipeline opt.
// Lane = (batch, h-row); 16 lanes/batch; 1024 waves = 1 wave/SIMD (hard cap).
//
// R6 evidence: per-ITERATION (4-step) cycles across R1/R2/R3/R4b cluster at
// ~900-1080 ~= one HBM round trip (m126 ~900 cyc) despite 2x differences in
// instruction count -> the old loop's register rotation (xc=xn; xn=xf)
// forced s_waitcnt vmcnt(0) every iteration; the loop was serialized on its
// own prefetch, not on compute. Fix: stage 16 timesteps/iteration into
// named buffers with an unroll-2 modulo pipeline (no copies, waits land a
// full 16-step block after issue). STEP is identical to R4b (best so far):
// fdot2 packed front + g-trick exp2 sigmoid tail.
//
// g-trick: state g = 1/(2^y+1), h = 1-2g; rowsum(W_hh) folds into bias,
// -2*S2LE into weights. Only g/W_hh are f16 (measured absmax ~2e-3 vs
// threshold 5.6e-3); accumulation f32 via v_dot2_f32_f16.

#define S2LE 2.8853900817779268f  // 2*log2(e)

typedef __fp16 half2_ __attribute__((ext_vector_type(2)));
typedef float float4_ __attribute__((ext_vector_type(4)));

#define ROTI(v, N) __builtin_amdgcn_mov_dpp((v), 0x120 + (N), 0xF, 0xF, 0)
#define ROTF(v, N) __int_as_float(__builtin_amdgcn_mov_dpp(__float_as_int(v), 0x120 + (N), 0xF, 0xF, 0))
#define ROTP(v, N) __builtin_bit_cast(half2_, __builtin_amdgcn_mov_dpp(__builtin_bit_cast(int, (v)), 0x120 + (N), 0xF, 0xF, 0))

__global__ __launch_bounds__(64) void rnn_kernel(
    const float* __restrict__ x,
    const float* __restrict__ W_ih,
    const float* __restrict__ W_hh,
    const float* __restrict__ b_ih,
    const float* __restrict__ b_hh,
    const float* __restrict__ W_fc,
    const float* __restrict__ b_fc,
    float* __restrict__ out)
{
    const int li = (int)(threadIdx.x & 15u);
    const int b  = (int)((blockIdx.x * 64u + threadIdx.x) >> 4);

    const float* __restrict__ row = W_hh + li * 16;

    float sw = 0.0f;
#pragma unroll
    for (int j = 0; j < 16; ++j) sw += row[j];

    const float wsc = -2.0f * S2LE;

    // Self-calibrated packed weights (verified R4b): w2[k] matches the pair
    // (g_s, g_{s^1}) arriving at this lane from ROTP(pk0, 2k).
    half2_ w2[8];
    {
        const int r1i = ROTI(li, 1);
        w2[0][0] = (__fp16)(wsc * row[li]);
        w2[0][1] = (__fp16)(wsc * row[r1i]);
#define LW(K, N) { int s0_ = ROTI(li, N); int s1_ = ROTI(r1i, N); \
        w2[K][0] = (__fp16)(wsc * row[s0_]); \
        w2[K][1] = (__fp16)(wsc * row[s1_]); }
        LW(1, 2) LW(2, 4) LW(3, 6) LW(4, 8) LW(5, 10) LW(6, 12) LW(7, 14)
#undef LW
    }

    const float wih  = W_ih[li] * S2LE;
    const float bias = (b_ih[li] + b_hh[li] + sw) * S2LE;
    const float wfc  = W_fc[li];
    const float bfc  = b_fc[0];

    const float4_* __restrict__ xv = (const float4_*)(x + (size_t)b * 512);

    float g = 0.5f;  // represents h = 0

#define STEP(XP) do { \
    float r1_ = ROTF(g, 1); \
    half2_ pk0 = __builtin_amdgcn_cvt_pkrtz(g, r1_); \
    half2_ p2_  = ROTP(pk0, 2); \
    half2_ p4_  = ROTP(pk0, 4); \
    half2_ p6_  = ROTP(pk0, 6); \
    half2_ p8_  = ROTP(pk0, 8); \
    half2_ p10_ = ROTP(pk0, 10); \
    half2_ p12_ = ROTP(pk0, 12); \
    half2_ p14_ = ROTP(pk0, 14); \
    float c0_ = __builtin_amdgcn_fdot2(pk0,  w2[0], (XP), false); \
    c0_ = __builtin_amdgcn_fdot2(p2_,  w2[1], c0_, false); \
    float c1_ = __builtin_amdgcn_fdot2(p4_,  w2[2], 0.0f, false); \
    c1_ = __builtin_amdgcn_fdot2(p6_,  w2[3], c1_, false); \
    float c2_ = __builtin_amdgcn_fdot2(p8_,  w2[4], 0.0f, false); \
    c2_ = __builtin_amdgcn_fdot2(p10_, w2[5], c2_, false); \
    float c3_ = __builtin_amdgcn_fdot2(p12_, w2[6], 0.0f, false); \
    c3_ = __builtin_amdgcn_fdot2(p14_, w2[7], c3_, false); \
    float s_ = (c0_ + c1_) + (c2_ + c3_); \
    float e_ = __builtin_amdgcn_exp2f(s_); \
    g = __builtin_amdgcn_rcpf(e_ + 1.0f); \
} while (0)

// 16 recurrent steps from a 4-x-float4 staged block.
#define BLOCK(BUF) do { \
    _Pragma("unroll") \
    for (int j = 0; j < 4; ++j) { \
        STEP(fmaf((BUF)[j][0], wih, bias)); \
        STEP(fmaf((BUF)[j][1], wih, bias)); \
        STEP(fmaf((BUF)[j][2], wih, bias)); \
        STEP(fmaf((BUF)[j][3], wih, bias)); \
    } \
} while (0)

    float4_ bufA[4], bufB[4];
#pragma unroll
    for (int j = 0; j < 4; ++j) bufA[j] = xv[j];  // block 0

    // Unroll-2 modulo pipeline over 32 blocks of 16 timesteps. Loads for a
    // block are issued one full block (~2000+ cyc of compute) before use;
    // no register rotation -> no per-iteration vmcnt(0) drain.
#pragma unroll 1
    for (int i = 0; i < 32; i += 2) {
#pragma unroll
        for (int j = 0; j < 4; ++j) bufB[j] = xv[(4 * (i + 1) + j) & 127];
        BLOCK(bufA);
#pragma unroll
        for (int j = 0; j < 4; ++j) bufA[j] = xv[(4 * (i + 2) + j) & 127];
        BLOCK(bufB);
    }
#undef BLOCK
#undef STEP

    // out[b] = sum_i wfc_i * h_i + bfc,  h = 1 - 2g (exact f32 g).
    float p = fmaf(-2.0f * wfc, g, wfc);
    p += ROTF(p, 8);
    p += ROTF(p, 4);
    p += ROTF(p, 2);
    p += ROTF(p, 1);
    if (li == 0) out[b] = p + bfc;
}

extern "C" void kernel_launch(void* const* d_in, const int* in_sizes, int n_in,
                              void* d_out, int out_size, void* d_ws, size_t ws_size,
                              hipStream_t stream) {
    const float* x    = (const float*)d_in[0];
    const float* W_ih = (const float*)d_in[1];
    const float* W_hh = (const float*)d_in[2];
    const float* b_ih = (const float*)d_in[3];
    const float* b_hh = (const float*)d_in[4];
    const float* W_fc = (const float*)d_in[5];
    const float* b_fc = (const float*)d_in[6];
    float* out = (float*)d_out;

    rnn_kernel<<<1024, 64, 0, stream>>>(x, W_ih, W_hh, b_ih, b_hh, W_fc, b_fc, out);
}

// Round 8
// 94.923 us; speedup vs baseline: 1.2626x; 1.0825x over previous
//
#include <hip/hip_runtime.h>

// Vanilla RNN B=4096 S=512 I=1 H=16 O=1 — serial-chain latency optimization.
// Lane = (batch, h-row); 16 lanes/batch; 1024 waves = 1 wave/SIMD (hard cap).
// Wall time = 512 * per-step critical-path latency (all batches parallel).
//
// R7: matvec as 16 hand-written v_fmac_f32_dpp/v_mul_f32_dpp (row_ror:N)
// in ONE asm block — the fold the compiler refused in R2. Pure VOP2 2-cyc
// issue, no pack/rotate hops, no VOP3P. All-f32 datapath again (absmax
// back to ~1e-5). Keeps: g-trick exp2 tail (best measured), R6's staged
// 16-step load pipeline (removed per-iter vmcnt drain), self-calibrated
// weights (builtin ctrl 0x120+N == row_ror:N — exact same instruction,
// mapping validated end-to-end in R1).
//
// g-trick: state g = 1/(2^y+1), h = 1-2g; rowsum(W_hh) folds into bias,
// -2*S2LE into the weights; S2LE = 2*log2(e) pre-scales for exp2.
// s_nop 1 at asm head: gfx9 hazard "VALU writes VGPR -> DPP reads it as
// src0" needs 2 wait states (g is produced by v_rcp just before).

#define S2LE 2.8853900817779268f  // 2*log2(e)

typedef float float4_ __attribute__((ext_vector_type(4)));

#define ROTI(v, N) __builtin_amdgcn_mov_dpp((v), 0x120 + (N), 0xF, 0xF, 0)
#define ROTF(v, N) __int_as_float(__builtin_amdgcn_mov_dpp(__float_as_int(v), 0x120 + (N), 0xF, 0xF, 0))

__global__ __launch_bounds__(64) void rnn_kernel(
    const float* __restrict__ x,
    const float* __restrict__ W_ih,
    const float* __restrict__ W_hh,
    const float* __restrict__ b_ih,
    const float* __restrict__ b_hh,
    const float* __restrict__ W_fc,
    const float* __restrict__ b_fc,
    float* __restrict__ out)
{
    const int li = (int)(threadIdx.x & 15u);
    const int b  = (int)((blockIdx.x * 64u + threadIdx.x) >> 4);

    const float* __restrict__ row = W_hh + li * 16;

    float sw = 0.0f;
#pragma unroll
    for (int j = 0; j < 16; ++j) sw += row[j];

    const float wsc = -2.0f * S2LE;

    // Self-calibrated weights: w[N] = wsc * W[li][sigma_N(li)] where sigma_N
    // is the HW's row_ror:N permutation (R1-validated).
    float w0  = wsc * row[li];
    float w1  = wsc * row[ROTI(li, 1)];
    float w2  = wsc * row[ROTI(li, 2)];
    float w3  = wsc * row[ROTI(li, 3)];
    float w4  = wsc * row[ROTI(li, 4)];
    float w5  = wsc * row[ROTI(li, 5)];
    float w6  = wsc * row[ROTI(li, 6)];
    float w7  = wsc * row[ROTI(li, 7)];
    float w8  = wsc * row[ROTI(li, 8)];
    float w9  = wsc * row[ROTI(li, 9)];
    float w10 = wsc * row[ROTI(li, 10)];
    float w11 = wsc * row[ROTI(li, 11)];
    float w12 = wsc * row[ROTI(li, 12)];
    float w13 = wsc * row[ROTI(li, 13)];
    float w14 = wsc * row[ROTI(li, 14)];
    float w15 = wsc * row[ROTI(li, 15)];

    const float wih  = W_ih[li] * S2LE;
    const float bias = (b_ih[li] + b_hh[li] + sw) * S2LE;
    const float wfc  = W_fc[li];
    const float bfc  = b_fc[0];

    const float4_* __restrict__ xv = (const float4_*)(x + (size_t)b * 512);

    float g = 0.5f;  // represents h = 0

    // One step: a0 starts at xp (tied "+v"); 4 round-robin DPP-MAC chains
    // of depth 4; tree add; exp2 -> add -> rcp tail.
#define STEP(XP) do { \
    float a0 = (XP), a1, a2, a3; \
    asm volatile( \
        "s_nop 1\n\t" \
        "v_fmac_f32 %0, %4, %5\n\t" \
        "v_mul_f32_dpp %1, %4, %9  row_ror:4  row_mask:0xf bank_mask:0xf\n\t" \
        "v_mul_f32_dpp %2, %4, %13 row_ror:8  row_mask:0xf bank_mask:0xf\n\t" \
        "v_mul_f32_dpp %3, %4, %17 row_ror:12 row_mask:0xf bank_mask:0xf\n\t" \
        "v_fmac_f32_dpp %0, %4, %6  row_ror:1  row_mask:0xf bank_mask:0xf\n\t" \
        "v_fmac_f32_dpp %1, %4, %10 row_ror:5  row_mask:0xf bank_mask:0xf\n\t" \
        "v_fmac_f32_dpp %2, %4, %14 row_ror:9  row_mask:0xf bank_mask:0xf\n\t" \
        "v_fmac_f32_dpp %3, %4, %18 row_ror:13 row_mask:0xf bank_mask:0xf\n\t" \
        "v_fmac_f32_dpp %0, %4, %7  row_ror:2  row_mask:0xf bank_mask:0xf\n\t" \
        "v_fmac_f32_dpp %1, %4, %11 row_ror:6  row_mask:0xf bank_mask:0xf\n\t" \
        "v_fmac_f32_dpp %2, %4, %15 row_ror:10 row_mask:0xf bank_mask:0xf\n\t" \
        "v_fmac_f32_dpp %3, %4, %19 row_ror:14 row_mask:0xf bank_mask:0xf\n\t" \
        "v_fmac_f32_dpp %0, %4, %8  row_ror:3  row_mask:0xf bank_mask:0xf\n\t" \
        "v_fmac_f32_dpp %1, %4, %12 row_ror:7  row_mask:0xf bank_mask:0xf\n\t" \
        "v_fmac_f32_dpp %2, %4, %16 row_ror:11 row_mask:0xf bank_mask:0xf\n\t" \
        "v_fmac_f32_dpp %3, %4, %20 row_ror:15 row_mask:0xf bank_mask:0xf\n\t" \
        : "+v"(a0), "=&v"(a1), "=&v"(a2), "=&v"(a3) \
        : "v"(g), \
          "v"(w0),  "v"(w1),  "v"(w2),  "v"(w3), \
          "v"(w4),  "v"(w5),  "v"(w6),  "v"(w7), \
          "v"(w8),  "v"(w9),  "v"(w10), "v"(w11), \
          "v"(w12), "v"(w13), "v"(w14), "v"(w15)); \
    float s_ = (a0 + a1) + (a2 + a3); \
    float e_ = __builtin_amdgcn_exp2f(s_); \
    g = __builtin_amdgcn_rcpf(e_ + 1.0f); \
} while (0)

// 16 recurrent steps from a 4-x-float4 staged block.
#define BLOCK(BUF) do { \
    _Pragma("unroll") \
    for (int j = 0; j < 4; ++j) { \
        STEP(fmaf((BUF)[j][0], wih, bias)); \
        STEP(fmaf((BUF)[j][1], wih, bias)); \
        STEP(fmaf((BUF)[j][2], wih, bias)); \
        STEP(fmaf((BUF)[j][3], wih, bias)); \
    } \
} while (0)

    float4_ bufA[4], bufB[4];
#pragma unroll
    for (int j = 0; j < 4; ++j) bufA[j] = xv[j];  // block 0

    // Unroll-2 modulo pipeline over 32 blocks of 16 timesteps (R6): loads
    // issue one full block ahead; no register rotation, no per-iter drain.
#pragma unroll 1
    for (int i = 0; i < 32; i += 2) {
#pragma unroll
        for (int j = 0; j < 4; ++j) bufB[j] = xv[(4 * (i + 1) + j) & 127];
        BLOCK(bufA);
#pragma unroll
        for (int j = 0; j < 4; ++j) bufA[j] = xv[(4 * (i + 2) + j) & 127];
        BLOCK(bufB);
    }
#undef BLOCK
#undef STEP

    // out[b] = sum_i wfc_i * h_i + bfc,  h = 1 - 2g (exact f32 g).
    float p = fmaf(-2.0f * wfc, g, wfc);
    p += ROTF(p, 8);
    p += ROTF(p, 4);
    p += ROTF(p, 2);
    p += ROTF(p, 1);
    if (li == 0) out[b] = p + bfc;
}

extern "C" void kernel_launch(void* const* d_in, const int* in_sizes, int n_in,
                              void* d_out, int out_size, void* d_ws, size_t ws_size,
                              hipStream_t stream) {
    const float* x    = (const float*)d_in[0];
    const float* W_ih = (const float*)d_in[1];
    const float* W_hh = (const float*)d_in[2];
    const float* b_ih = (const float*)d_in[3];
    const float* b_hh = (const float*)d_in[4];
    const float* W_fc = (const float*)d_in[5];
    const float* b_fc = (const float*)d_in[6];
    float* out = (float*)d_out;

    rnn_kernel<<<1024, 64, 0, stream>>>(x, W_ih, W_hh, b_ih, b_hh, W_fc, b_fc, out);
}